// Round 6
// baseline (284.409 us; speedup 1.0000x reference)
//
#include <hip/hip_runtime.h>

// ABLATION ROUND (v6): phase-timing instrumentation of the v2 kernel.
// Three co-launched variants on one stream, in order:
//   MODE1: P0 only            - 1024 blocks x 6 cold tiles each (6x dur)
//   MODE2: P0+P12             - 1024 blocks x 6 cold tiles each (6x dur)
//   MODE0: full v2 kernel     - 6144 blocks, runs LAST, overwrites out fully
// MODE1/2 write garbage keep-alive values into out[0..262143]; MODE0
// overwrites every output element afterward -> final output correct.
// Keep-alive = scattered dynamic LDS read -> 1 global store per thread per
// tile (defeats DCE of the ablated pipeline; guide rule #17).
// Readout: headline ~= tM1 + tM2 + tfull + 115us fixed overhead (R1/R2/R3/R5
// all show +112..116); top-5 rows show MODE2 (~6*(tP0+tP12)). Solve:
//   tP0+tP12 = MODE2row/6 ;  tP0 = (headline-115-MODE2row-70)/6 ;
//   tP3 = 70 - (tP0+tP12).
// Kernel structure (v2, best at 69.4us): per 64x64 tile,
//   P0 : colmin global->regs->LDS (B: 86 rows x stride 116)
//   P12: rowmin -> border -> rowmax in regs (f4 LDS I/O, 2 barriers)
//   P3 : colmax -> coalesced store

#define HH 1024
#define WW 1024
#define KW 22
#define SB 116
#define PINF __builtin_inff()

template<bool IS_MIN>
__device__ __forceinline__ float vop(float a, float b) {
    return IS_MIN ? fminf(a, b) : fmaxf(a, b);
}

// van Herk / Gil-Werman, compile-time output count COUT (window KW=22).
template<bool IS_MIN, int COUT, class Get, class Put>
__device__ __forceinline__ void vanherk(Get get, Put put) {
    constexpr int NIN = COUT + KW - 1;
    constexpr int NB = (NIN + KW - 1) / KW;
    const float ID = IS_MIN ? PINF : -PINF;
    float Sprev[KW];
    #pragma unroll
    for (int j = 0; j < NB; ++j) {
        const int base = KW * j;
        const int needed = (NIN - base) < KW ? (NIN - base) : KW;
        float v[KW];
        #pragma unroll
        for (int m = 0; m < KW; ++m)
            if (m < needed) v[m] = get(base + m);
        float p = ID;
        #pragma unroll
        for (int m = 0; m < KW; ++m) {
            if (m < needed) {
                p = vop<IS_MIN>(p, v[m]);
                const int k = base - (KW - 1) + m;
                if (k >= 0 && k < COUT) {
                    if (m == KW - 1) put(k, p);
                    else             put(k, vop<IS_MIN>(Sprev[m + 1], p));
                }
            }
        }
        if (j < NB - 1) {
            float s = ID;
            #pragma unroll
            for (int m = KW - 1; m >= 0; --m) {
                s = vop<IS_MIN>(s, v[m]);
                Sprev[m] = s;
            }
        }
    }
}

// MODE: 0 = full, 1 = P0 only, 2 = P0+P12 (compile-time; barriers stay
// uniform across the block since MODE is a template parameter).
template<bool INTERIOR, int MODE>
__device__ __forceinline__ void tile_body(const float* __restrict__ src,
                                          float* __restrict__ dst,
                                          int R, int C, float* B, int t) {
    const int w = t >> 6, slot = t & 63;

    // ---- P0: colmin, global -> B rows [0,86) x cols j in [0,108). ----
    if (slot < 54) {
        const int ch = w >> 1;
        const int j = (w & 1) * 54 + slot;
        const int base_o = ch * 43;
        int cj = C - 22 + j;
        bool colOK = true;
        if (!INTERIOR) {
            colOK = (unsigned)cj < WW;
            cj = cj < 0 ? 0 : (cj > WW - 1 ? WW - 1 : cj);
        }
        const float* col = src + cj;
        const int rbase = R - 22 + base_o;
        vanherk<true, 43>(
            [&](int p) {
                int r = rbase + p;
                if (INTERIOR) return col[r * WW];
                int rc = r < 0 ? 0 : (r > HH - 1 ? HH - 1 : r);
                float vv = col[rc * WW];
                return (colOK && (unsigned)r < HH) ? vv : PINF;
            },
            [&](int k, float vv) { B[(base_o + k) * SB + j] = vv; });
    }
    __syncthreads();

    // ---- P12: fused rowmin -> border override -> rowmax, in regs. ----
    if constexpr (MODE != 1) {
        const bool act = t < 255;
        const int ch = (3 * t + 2) >> 8;          // t/85 for t<255
        const int o = t - 85 * ch;
        const int g0 = 5 * ch;                    // c0 = 20ch = 4*g0
        const int c0 = 20 * ch;
        float* Brow = B + o * SB;
        float in12[68];
        if (act) {
            #pragma unroll
            for (int i = 0; i < 17; ++i) {        // B cols [20ch, 20ch+68)
                float4 x = ((const float4*)Brow)[g0 + i];
                in12[4 * i] = x.x; in12[4 * i + 1] = x.y;
                in12[4 * i + 2] = x.z; in12[4 * i + 3] = x.w;
            }
        }
        float rx[24];
        if (act) {
            float er[45];
            vanherk<true, 45>(
                [&](int p) { return in12[p]; },
                [&](int k, float vv) { er[k] = vv; });
            if (!INTERIOR) {
                const bool rOK = (unsigned)(R - 11 + o) < HH;
                #pragma unroll
                for (int k = 0; k < 45; ++k) {
                    const int cimg = C - 11 + c0 + k;
                    if (!rOK || (unsigned)cimg >= WW) er[k] = -PINF;
                }
            }
            vanherk<false, 24>(
                [&](int p) { return er[p]; },
                [&](int k, float vv) { rx[k] = vv; });
        }
        __syncthreads();                          // all reads before any write
        if (act) {
            #pragma unroll
            for (int i = 0; i < 6; ++i)           // rowmax cols [20ch, 20ch+24)
                ((float4*)Brow)[g0 + i] =
                    make_float4(rx[4 * i], rx[4 * i + 1],
                                rx[4 * i + 2], rx[4 * i + 3]);
        }
        __syncthreads();
    }

    // ---- P3: colmax -> out. 64 cols x 4 chunks of 16 rows. ----
    if constexpr (MODE == 0) {
        const int c = t & 63;
        const int y0 = (t >> 6) << 4;             // {0,16,32,48}
        float o16[16];
        vanherk<false, 16>(
            [&](int p) { return B[(y0 + p) * SB + c]; },
            [&](int k, float vv) { o16[k] = vv; });
        #pragma unroll
        for (int k = 0; k < 16; ++k)
            dst[(R + y0 + k) * WW + C + c] = o16[k];
    }
}

template<int MODE>
__global__ __launch_bounds__(256, 4) void fused_open(const float* __restrict__ in,
                                                     float* __restrict__ out,
                                                     int nb, int nt) {
    __shared__ float B[86 * SB];                  // 39,904 B -> 4 blk/CU
    const int t = threadIdx.x;
    for (int it = 0; it < nt; ++it) {
        const int b = blockIdx.x + it * nb;       // cold tile each iteration
        const int plane = b >> 8;
        const int by = (b >> 4) & 15;
        const int bx = b & 15;
        const int R = by * 64, C = bx * 64;
        const float* src = in + (size_t)plane * (HH * WW);
        float* dst = out + (size_t)plane * (HH * WW);

        if (by >= 1 && by <= 14 && bx >= 1 && bx <= 14)
            tile_body<true, MODE>(src, dst, R, C, B, t);
        else
            tile_body<false, MODE>(src, dst, R, C, B, t);

        if constexpr (MODE != 0) {
            // keep-alive: scattered dynamic LDS read -> tiny store into a
            // region MODE0 overwrites later. Defeats DCE of ablated phases.
            const unsigned h = (t * 911u + (unsigned)it * 97u + 13u) % (86u * SB);
            out[(size_t)((b & 1023) * 256 + t)] = B[h];
            __syncthreads();                      // B reused next iteration
        }
    }
}

extern "C" void kernel_launch(void* const* d_in, const int* in_sizes, int n_in,
                              void* d_out, int out_size, void* d_ws, size_t ws_size,
                              hipStream_t stream) {
    const float* in = (const float*)d_in[0];
    float* out = (float*)d_out;
    (void)d_ws; (void)ws_size;
    // Ablation probes (write garbage into out[0..262143], overwritten below).
    // 1024 blocks = exactly 4 resident/CU; 6 cold tiles each (6144 = 1024*6).
    fused_open<1><<<1024, 256, 0, stream>>>(in, out, 1024, 6);   // P0 only
    fused_open<2><<<1024, 256, 0, stream>>>(in, out, 1024, 6);   // P0+P12
    // Real kernel: full pipeline, covers every tile, overwrites all of out.
    fused_open<0><<<6144, 256, 0, stream>>>(in, out, 6144, 1);
}

// Round 7
// 271.874 us; speedup vs baseline: 1.0461x; 1.0461x over previous
//
#include <hip/hip_runtime.h>

// Fused morphological opening (22x22 flat SE), 8x3x1024x1024 f32, one kernel.
// opening = dilate(erode(x)); separable and ORDER-FREE: erode = rowmin o
// colmin = colmin o rowmin. v7 reorders the pipeline so the GLOBAL phase is
// row-contiguous (R6 ablation: P0 was ~75% of kernel time at 27% of HBM BW
// -> issue-bound on 13.8K scalar column-major loads/tile).
// Per 64x64 output tile (B: 106 rows x stride 92, 39,008 B -> 4 blk/CU):
//   P0' : rowmin, global->regs->LDS. Thread owns (row, half): 17 f4 global
//         loads (vs 64 scalar), vanherk rowmin, 11 f4 LDS writes.
//   P12': fused colmin -> border override -> colmax, per column, in regs.
//         vanherk reads LDS column directly (no staging array).
//   P3' : rowmax from LDS rows (14 f4 reads) -> 8 f4 global stores.
// EVERY phase is balanced per WAVE INDEX (waves map one-per-SIMD):
//   P0' : 53 lanes/wave x 4 = 212 units = 106 rows x 2 col-halves
//         (half h: out cols [44h,44h+44), in x cols [C-24+44h, C+44h+44))
//   P12': 43 lanes/wave x 4 = 172 units = 86 cols x 2 row-chunks (L=32);
//         chunk reads B rows [32c,32c+74), erodes 53, dilates 32,
//         writes rows [32c,32c+32) in-place (read-all|barrier|write)
//   P3' : 32 lanes/wave x 4 = 128 units = 64 rows x 2 col-halves
// 3 barriers/tile, same as v2. Border tiles (block-uniform branch) take a
// scalar clamped-load path. B stride 92 dwords: scalar col ops (lanes =
// consecutive cols) conflict-free; f4 row ops start-bank 28*lane mod 32
// (gcd 4) ~4-way - accepted (m136: 4-way = 1.58x, only on f4 phases).
// Occupancy experiments (v3 remat disaster, v4 small-tile tax, v5 big-tile
// neutral) fixed the geometry at 64x64/256thr/4blk; this round attacks the
// measured phase cost instead. Window for index i: [i-11, i+10]. Erosion
// pads +inf; eroded values outside the image are -inf for dilation.

#define HH 1024
#define WW 1024
#define KW 22
#define SB 92
#define PINF __builtin_inff()

template<bool IS_MIN>
__device__ __forceinline__ float vop(float a, float b) {
    return IS_MIN ? fminf(a, b) : fmaxf(a, b);
}

// van Herk / Gil-Werman, compile-time output count COUT (window KW=22).
// get(p): input at window-space p (output k's window = get(k..k+21)).
template<bool IS_MIN, int COUT, class Get, class Put>
__device__ __forceinline__ void vanherk(Get get, Put put) {
    constexpr int NIN = COUT + KW - 1;
    constexpr int NB = (NIN + KW - 1) / KW;
    const float ID = IS_MIN ? PINF : -PINF;
    float Sprev[KW];
    #pragma unroll
    for (int j = 0; j < NB; ++j) {
        const int base = KW * j;
        const int needed = (NIN - base) < KW ? (NIN - base) : KW;
        float v[KW];
        #pragma unroll
        for (int m = 0; m < KW; ++m)
            if (m < needed) v[m] = get(base + m);
        float p = ID;
        #pragma unroll
        for (int m = 0; m < KW; ++m) {
            if (m < needed) {
                p = vop<IS_MIN>(p, v[m]);
                const int k = base - (KW - 1) + m;
                if (k >= 0 && k < COUT) {
                    if (m == KW - 1) put(k, p);
                    else             put(k, vop<IS_MIN>(Sprev[m + 1], p));
                }
            }
        }
        if (j < NB - 1) {
            float s = ID;
            #pragma unroll
            for (int m = KW - 1; m >= 0; --m) {
                s = vop<IS_MIN>(s, v[m]);
                Sprev[m] = s;
            }
        }
    }
}

template<bool INTERIOR>
__device__ __forceinline__ void tile_body(const float* __restrict__ src,
                                          float* __restrict__ dst,
                                          int R, int C, float* B, int t) {
    const int w = t >> 6, slot = t & 63;

    // ---- P0': rowmin, global -> B rows [0,106) x cols [0,88). ----
    // B[i][c] = min x[R-22+i][C-22+c .. C-1+c]  (c = eroded col C-11+c).
    // unit = (row i, col-half h): 212 = 106 x 2; 53 lanes/wave.
    // Loads x cols [a0, a0+68), a0 = C-24+44h (16B-aligned); window offset 2.
    {
        const bool act = slot < 53;
        if (act) {
            const int unit = w * 53 + slot;       // 0..211
            const int h = unit >= 106;            // wave-uniform (w<2 -> 0)
            const int i = unit - 106 * h;
            const int r = R - 22 + i;
            const int a0 = C - 24 + 44 * h;
            float in[68];
            if (INTERIOR) {
                const float* rowp = src + (size_t)r * WW + a0;
                #pragma unroll
                for (int q = 0; q < 17; ++q) {
                    const float4 x4 = ((const float4*)rowp)[q];
                    in[4 * q] = x4.x; in[4 * q + 1] = x4.y;
                    in[4 * q + 2] = x4.z; in[4 * q + 3] = x4.w;
                }
            } else {
                const bool rOK = (unsigned)r < HH;
                const int rc = r < 0 ? 0 : (r > HH - 1 ? HH - 1 : r);
                const float* rowp = src + (size_t)rc * WW;
                #pragma unroll
                for (int q = 0; q < 68; ++q) {
                    const int gc = a0 + q;
                    const bool cOK = (unsigned)gc < WW;
                    const int gcc = gc < 0 ? 0 : (gc > WW - 1 ? WW - 1 : gc);
                    const float vv = rowp[gcc];
                    in[q] = (rOK && cOK) ? vv : PINF;
                }
            }
            float rm[44];
            vanherk<true, 44>(
                [&](int p) { return in[2 + p]; },
                [&](int k, float vv) { rm[k] = vv; });
            float4* bout = (float4*)(B + i * SB + 44 * h);
            #pragma unroll
            for (int q = 0; q < 11; ++q)
                bout[q] = make_float4(rm[4 * q], rm[4 * q + 1],
                                      rm[4 * q + 2], rm[4 * q + 3]);
        }
    }
    __syncthreads();

    // ---- P12': fused colmin -> border override -> colmax, in regs. ----
    // unit = (col, row-chunk c): 172 = 86 x 2; 43 lanes/wave; chunk c
    // outputs rows [32c, 32c+32), reads B rows [32c, 32c+74) directly from
    // LDS inside vanherk (each p read once). er[k] = eroded at global row
    // R+32c-11+k, col C-11+col; OOB -> -inf. Writes in place rows
    // [32c,32c+32): all reads pre-barrier, writes post-barrier.
    {
        const bool act = slot < 43;
        const int unit = w * 43 + (act ? slot : 0);  // 0..171
        const int ch = unit >= 86;                   // wave-uniform
        const int col = unit - 86 * ch;
        const int base = 32 * ch;
        float cm[32];
        if (act) {
            const float* colp = B + col;
            float er[53];
            vanherk<true, 53>(
                [&](int p) { return colp[(base + p) * SB]; },
                [&](int k, float vv) { er[k] = vv; });
            if (!INTERIOR) {
                const int gc = C - 11 + col;
                const bool cOK = (unsigned)gc < WW;
                #pragma unroll
                for (int k = 0; k < 53; ++k) {
                    const int ge = R + base - 11 + k;
                    if (!cOK || (unsigned)ge >= HH) er[k] = -PINF;
                }
            }
            vanherk<false, 32>(
                [&](int p) { return er[p]; },
                [&](int k, float vv) { cm[k] = vv; });
        }
        __syncthreads();                          // all reads before any write
        if (act) {
            #pragma unroll
            for (int k = 0; k < 32; ++k)
                B[(base + k) * SB + col] = cm[k];
        }
        __syncthreads();
    }

    // ---- P3': rowmax -> out. unit = (row y, col-half h): 128 = 64 x 2. ----
    // out[R+y][C+32h+m] = max cm[y][32h+m .. 32h+m+21]; 14 f4 LDS reads
    // (cols [32h, 32h+56); 54..55 unused), 8 f4 global stores.
    {
        const bool act = slot < 32;
        if (act) {
            const int unit = w * 32 + slot;       // 0..127
            const int y = unit & 63;
            const int h = unit >> 6;              // wave-uniform (w<2 -> 0)
            const float* cp = B + y * SB + 32 * h;
            float in3[56];
            #pragma unroll
            for (int q = 0; q < 14; ++q) {
                const float4 x4 = ((const float4*)cp)[q];
                in3[4 * q] = x4.x; in3[4 * q + 1] = x4.y;
                in3[4 * q + 2] = x4.z; in3[4 * q + 3] = x4.w;
            }
            float o32[32];
            vanherk<false, 32>(
                [&](int p) { return in3[p]; },
                [&](int k, float vv) { o32[k] = vv; });
            float4* op = (float4*)(dst + (size_t)(R + y) * WW + C + 32 * h);
            #pragma unroll
            for (int q = 0; q < 8; ++q)
                op[q] = make_float4(o32[4 * q], o32[4 * q + 1],
                                    o32[4 * q + 2], o32[4 * q + 3]);
        }
    }
}

__global__ __launch_bounds__(256, 4) void fused_open(const float* __restrict__ in,
                                                     float* __restrict__ out) {
    __shared__ float B[106 * SB];                 // 39,008 B -> 4 blk/CU
    const int t = threadIdx.x;
    const int b = blockIdx.x;
    const int plane = b >> 8;
    const int by = (b >> 4) & 15;
    const int bx = b & 15;
    const int R = by * 64, C = bx * 64;
    const float* src = in + (size_t)plane * (HH * WW);
    float* dst = out + (size_t)plane * (HH * WW);

    // interior: P0' touches img rows [R-22, R+83], cols [C-24, C+87]
    if (by >= 1 && by <= 14 && bx >= 1 && bx <= 14)
        tile_body<true>(src, dst, R, C, B, t);
    else
        tile_body<false>(src, dst, R, C, B, t);
}

extern "C" void kernel_launch(void* const* d_in, const int* in_sizes, int n_in,
                              void* d_out, int out_size, void* d_ws, size_t ws_size,
                              hipStream_t stream) {
    const float* in = (const float*)d_in[0];
    float* out = (float*)d_out;
    (void)d_ws; (void)ws_size;
    fused_open<<<24 * 16 * 16, 256, 0, stream>>>(in, out);
}